// Round 1
// baseline (121.414 us; speedup 1.0000x reference)
//
#include <hip/hip_runtime.h>
#include <hip/hip_bf16.h>

// InfoNCE fused: loss = (1/N) sum_i [ log(sum_j exp(sim_ij)) - sim_ii ]
// where sim = (z1/||z1||) @ (z2/||z2||)^T / tau.
// (logits = [pos, diag-masked row] with pos == sim_ii  =>  lse over full row.)
//
// z1s = bf16( z1n * log2(e)/tau )  so exp(sim) = exp2(MFMA output). Values in
// [-29, 29] in log2 domain -> plain fp32 sum of exp2 is overflow-safe; no
// online max needed.

typedef __bf16  bf16x8 __attribute__((ext_vector_type(8)));
typedef float   f32x4  __attribute__((ext_vector_type(4)));

#if __has_builtin(__builtin_amdgcn_exp2f)
#define EXP2F(x) __builtin_amdgcn_exp2f(x)
#else
#define EXP2F(x) exp2f(x)
#endif

#define DDIM        64      // feature dim
#define ROWB        128     // 128 bytes per row of bf16 (64 * 2)
#define BM          128     // rows per block
#define NWAVES      8       // 512 threads
#define WROWS       16      // rows per wave (16x16x32 MFMA)
#define CHUNK       64      // z2 cols staged in LDS per iteration
#define LDS_STRIDE  144     // bytes per LDS row: 64*2 + 16 pad -> 2-way bank alias only (free)
#define CS          8       // column splits (grid.y)

// ---------------------------------------------------------------- normalize
// One wave per row: L2-normalize, scale, cast to bf16.
__global__ __launch_bounds__(256) void norm_cast_kernel(
    const float* __restrict__ z, __hip_bfloat16* __restrict__ out,
    float scale, int nrows)
{
    int row  = (blockIdx.x * 256 + threadIdx.x) >> 6;
    int lane = threadIdx.x & 63;
    if (row >= nrows) return;
    float v  = z[row * DDIM + lane];
    float ss = v * v;
    #pragma unroll
    for (int off = 32; off; off >>= 1) ss += __shfl_xor(ss, off);
    float n = fmaxf(sqrtf(ss), 1e-12f);
    out[row * DDIM + lane] = __float2bfloat16((v / n) * scale);
}

// ---------------------------------------------------------------- main
__global__ __launch_bounds__(512) void infonce_main_kernel(
    const __hip_bfloat16* __restrict__ z1s,
    const __hip_bfloat16* __restrict__ z2s,
    float* __restrict__ rowsum,   // fp32, atomic-accumulated partial sums of 2^C
    float* __restrict__ posv,     // C_ii (log2-domain positive logit)
    int N)
{
    __shared__ char lds[CHUNK * LDS_STRIDE];

    const int tid  = threadIdx.x;
    const int wave = tid >> 6;
    const int lane = tid & 63;
    const int q    = lane >> 4;    // quad 0..3
    const int l15  = lane & 15;

    const int r0      = blockIdx.x * BM;
    const int colspan = N / CS;
    const int c0      = blockIdx.y * colspan;
    const int wr      = r0 + wave * WROWS;   // this wave's row base

    // A fragments: rows [wr, wr+16), k 0..63. A[m=lane&15][k=q*8+j].
    const char* abase = (const char*)z1s + (size_t)(wr + l15) * ROWB + q * 16;
    const bf16x8 a0 = *(const bf16x8*)(abase);        // k 0..31
    const bf16x8 a1 = *(const bf16x8*)(abase + 64);   // k 32..63

    float s0 = 0.f, s1 = 0.f, s2 = 0.f, s3 = 0.f;

    // staging indices: thread t -> col c = t/8, 16B piece p = t%8
    const int sc = tid >> 3, sp = tid & 7;

    for (int cc = 0; cc < colspan; cc += CHUNK) {
        __syncthreads();   // previous chunk's reads done
        // stage z2s[c0+cc .. +CHUNK) into LDS (padded rows)
        *(float4*)(lds + sc * LDS_STRIDE + sp * 16) =
            *(const float4*)((const char*)z2s + (size_t)(c0 + cc + sc) * ROWB + sp * 16);
        __syncthreads();

        #pragma unroll
        for (int ct = 0; ct < CHUNK / 16; ++ct) {
            const char* bbase = lds + (ct * 16 + l15) * LDS_STRIDE + q * 16;
            bf16x8 b0 = *(const bf16x8*)(bbase);
            bf16x8 b1 = *(const bf16x8*)(bbase + 64);
            f32x4 acc = {0.f, 0.f, 0.f, 0.f};
            acc = __builtin_amdgcn_mfma_f32_16x16x32_bf16(a0, b0, acc, 0, 0, 0);
            acc = __builtin_amdgcn_mfma_f32_16x16x32_bf16(a1, b1, acc, 0, 0, 0);

            const int cg = c0 + cc + ct * 16;  // global col base of this tile
            if (cg == wr) {                    // diagonal tile (wave-uniform, rare)
                // C/D: col = lane&15, row = q*4 + reg
                #pragma unroll
                for (int i = 0; i < 4; ++i)
                    if (l15 == q * 4 + i) posv[wr + q * 4 + i] = acc[i];
            }
            s0 += EXP2F(acc[0]);
            s1 += EXP2F(acc[1]);
            s2 += EXP2F(acc[2]);
            s3 += EXP2F(acc[3]);
        }
    }

    // each lane's s[i] is a partial of row (wr + q*4 + i) over its columns;
    // reduce across the 16 lanes of the quad.
    #pragma unroll
    for (int off = 1; off < 16; off <<= 1) {
        s0 += __shfl_xor(s0, off);
        s1 += __shfl_xor(s1, off);
        s2 += __shfl_xor(s2, off);
        s3 += __shfl_xor(s3, off);
    }
    if (l15 == 0) {
        atomicAdd(&rowsum[wr + q * 4 + 0], s0);
        atomicAdd(&rowsum[wr + q * 4 + 1], s1);
        atomicAdd(&rowsum[wr + q * 4 + 2], s2);
        atomicAdd(&rowsum[wr + q * 4 + 3], s3);
    }
}

// ---------------------------------------------------------------- finalize
__global__ __launch_bounds__(256) void finalize_kernel(
    const float* __restrict__ rowsum, const float* __restrict__ posv,
    float* __restrict__ out, float invN)
{
    int i = blockIdx.x * 256 + threadIdx.x;
    // loss_i = ln2 * (log2(rowsum_i) - C_ii) / N
    float c = 0.69314718055994531f * (log2f(rowsum[i]) - posv[i]) * invN;
    #pragma unroll
    for (int off = 32; off; off >>= 1) c += __shfl_down(c, off);
    if ((threadIdx.x & 63) == 0) atomicAdd(out, c);
}

// ---------------------------------------------------------------- launch
extern "C" void kernel_launch(void* const* d_in, const int* in_sizes, int n_in,
                              void* d_out, int out_size, void* d_ws, size_t ws_size,
                              hipStream_t stream)
{
    const float* z1 = (const float*)d_in[0];
    const float* z2 = (const float*)d_in[1];
    const int N = in_sizes[0] / DDIM;   // 16384

    char* ws = (char*)d_ws;
    __hip_bfloat16* z1s = (__hip_bfloat16*)ws;                        // N*64*2 = 2 MB
    __hip_bfloat16* z2s = (__hip_bfloat16*)(ws + (size_t)N * ROWB);   // 2 MB
    float* rowsum = (float*)(ws + 2 * (size_t)N * ROWB);              // N*4
    float* posv   = (float*)(ws + 2 * (size_t)N * ROWB + (size_t)N * 4);

    hipMemsetAsync(rowsum, 0, (size_t)N * sizeof(float), stream);
    hipMemsetAsync(d_out, 0, sizeof(float), stream);

    // log2(e)/tau folded into z1's normalization
    const float kScale = 28.853900817779268f;  // log2(e) / 0.05
    norm_cast_kernel<<<N / 4, 256, 0, stream>>>(z1, z1s, kScale, N);
    norm_cast_kernel<<<N / 4, 256, 0, stream>>>(z2, z2s, 1.0f, N);

    dim3 grid(N / BM, CS);
    infonce_main_kernel<<<grid, NWAVES * 64, 0, stream>>>(z1s, z2s, rowsum, posv, N);

    finalize_kernel<<<N / 256, 256, 0, stream>>>(rowsum, posv, (float*)d_out, 1.0f / N);
}